// Round 10
// baseline (947.798 us; speedup 1.0000x reference)
//
#include <hip/hip_runtime.h>
#include <stdint.h>

typedef __attribute__((ext_vector_type(4))) float f32x4;
typedef __attribute__((ext_vector_type(16))) float f32x16;
typedef __attribute__((ext_vector_type(8))) short s16x8;

#define MFMA16(A, B, C) __builtin_amdgcn_mfma_f32_16x16x32_bf16(A, B, C, 0, 0, 0)
#define MFMA32(A, B, C) __builtin_amdgcn_mfma_f32_32x32x16_bf16(A, B, C, 0, 0, 0)
#define WAIT_VM(N) asm volatile("s_waitcnt vmcnt(" #N ")" ::: "memory")
#define WAIT_LGKM() asm volatile("s_waitcnt lgkmcnt(0)" ::: "memory")
#define BAR() __builtin_amdgcn_s_barrier()
#define SCHED_FENCE() __builtin_amdgcn_sched_barrier(0)
#define SP1() __builtin_amdgcn_s_setprio(1)
#define SP0() __builtin_amdgcn_s_setprio(0)

#define PHASE_SYNC(N) do { SCHED_FENCE(); WAIT_LGKM(); WAIT_VM(N); BAR(); SCHED_FENCE(); } while (0)

__device__ __forceinline__ unsigned short f2bf(float x) {
  union { float f; unsigned u; } v; v.f = x;
  return (unsigned short)((v.u + 0x7fffu + ((v.u >> 16) & 1u)) >> 16);
}

// ---------------- cast f32 -> bf16, 4 elems/thread ----------------
__global__ void k_cast_bf16(const float* __restrict__ in, unsigned short* __restrict__ out, int n4) {
  int i = blockIdx.x * blockDim.x + threadIdx.x;
  const int stride = gridDim.x * blockDim.x;
  for (; i < n4; i += stride) {
    const float4 v = ((const float4*)in)[i];
    ushort4 o;
    o.x = f2bf(v.x); o.y = f2bf(v.y); o.z = f2bf(v.z); o.w = f2bf(v.w);
    ((ushort4*)out)[i] = o;
  }
}

// ---------------- exc [16384][28] -> excT bf16 [32][16384] (rows 28..31 = 0) + b[28] ----------------
__global__ void k_excT(const float* __restrict__ exc, unsigned short* __restrict__ excT,
                       float* __restrict__ bvec) {
  const int c = blockIdx.x;        // 0..31
  const int tid = threadIdx.x;     // 256
  float sum = 0.f;
  for (int j = tid; j < 16384; j += 256) {
    const float v = (c < 28) ? exc[(size_t)j * 28 + c] : 0.f;
    excT[(size_t)c * 16384 + j] = f2bf(v);
    sum += v;
  }
  #pragma unroll
  for (int o = 32; o; o >>= 1) sum += __shfl_down(sum, o, 64);
  __shared__ float wsum[4];
  if ((tid & 63) == 0) wsum[tid >> 6] = sum;
  __syncthreads();
  if (tid == 0 && c < 28) bvec[c] = fmaxf(wsum[0] + wsum[1] + wsum[2] + wsum[3], 1.0f);
}

// ================= k_proj (unchanged working engine) =================
__device__ __forceinline__ void stage_a(const unsigned short* __restrict__ src, int ld,
                                        unsigned short* smem, int dsoff, int w, int offsrc) {
  #pragma unroll
  for (int c = 0; c < 4; ++c)
    __builtin_amdgcn_global_load_lds(
        (const __attribute__((address_space(1))) unsigned int*)(src + offsrc + c * 64 * ld),
        (__attribute__((address_space(3))) unsigned int*)(smem + dsoff + c * 4096 + w * 512),
        16, 0, 0);
}
__device__ __forceinline__ void stage_b(const unsigned short* __restrict__ src, int ld,
                                        unsigned short* smem, int dsoff, int w, int offsrc) {
  #pragma unroll
  for (int c = 0; c < 2; ++c)
    __builtin_amdgcn_global_load_lds(
        (const __attribute__((address_space(1))) unsigned int*)(src + offsrc + c * 64 * ld),
        (__attribute__((address_space(3))) unsigned int*)(smem + dsoff + c * 4096 + w * 512),
        16, 0, 0);
}

__device__ __forceinline__ void mma_step_p(const unsigned short* smem, int ao, int bo,
                                           int wr, int wc, int r, int q, f32x4 acc[8][2]) {
  const int rx = r & 7;
  #pragma unroll
  for (int ks = 0; ks < 2; ++ks) {
    const int sb = ((ks * 4 + q) ^ rx) << 3;
    s16x8 bf[2];
    #pragma unroll
    for (int j = 0; j < 2; ++j)
      bf[j] = *(const s16x8*)(smem + bo + (wc * 32 + j * 16 + r) * 64 + sb);
    #pragma unroll
    for (int i = 0; i < 8; ++i) {
      const s16x8 af = *(const s16x8*)(smem + ao + (wr * 128 + i * 16 + r) * 64 + sb);
      #pragma unroll
      for (int j = 0; j < 2; ++j)
        acc[i][j] = MFMA16(af, bf[j], acc[i][j]);
    }
  }
}

#define PA0 0
#define PB0 16384
#define PA1 24576
#define PB1 40960

__global__ __launch_bounds__(512, 2) void k_proj(const unsigned short* __restrict__ featbf,
                                                 const unsigned short* __restrict__ exbf,
                                                 const unsigned short* __restrict__ gwbf,
                                                 const float* __restrict__ gb,
                                                 float* __restrict__ fall) {
  __shared__ __align__(16) unsigned short smem[49152];  // 96 KB
  const int tid = threadIdx.x, w = tid >> 6, lane = tid & 63;
  const int wr = w >> 2, wc = w & 3, r = lane & 15, q = lane >> 4;
  const int offsrc = (w * 8 + (lane >> 3)) * 1024 + (((lane & 7) ^ (lane >> 3)) << 3);
  const int m0 = blockIdx.x * 256;
  const int n0 = blockIdx.y * 128;
  const unsigned short* Asrc = (m0 < 8192) ? (featbf + (size_t)m0 * 1024)
                                           : (exbf + (size_t)(m0 - 8192) * 1024);
  const unsigned short* Bsrc = gwbf + (size_t)n0 * 1024;
  f32x4 acc[8][2];
  #pragma unroll
  for (int i = 0; i < 8; ++i)
    #pragma unroll
    for (int j = 0; j < 2; ++j) acc[i][j] = {0.f, 0.f, 0.f, 0.f};

  stage_a(Asrc, 1024, smem, PA0, w, offsrc);
  stage_b(Bsrc, 1024, smem, PB0, w, offsrc);
  for (int t = 0; t < 15; ++t) {
    const int na = ((t + 1) & 1) ? PA1 : PA0, nbb = ((t + 1) & 1) ? PB1 : PB0;
    stage_a(Asrc + (t + 1) * 64, 1024, smem, na, w, offsrc);
    stage_b(Bsrc + (t + 1) * 64, 1024, smem, nbb, w, offsrc);
    WAIT_VM(6);
    BAR();
    mma_step_p(smem, (t & 1) ? PA1 : PA0, (t & 1) ? PB1 : PB0, wr, wc, r, q, acc);
    WAIT_LGKM();
    BAR();
  }
  WAIT_VM(0);
  BAR();
  mma_step_p(smem, PA1, PB1, wr, wc, r, q, acc);

  #pragma unroll
  for (int j = 0; j < 2; ++j) {
    const int col = n0 + wc * 32 + j * 16 + r;
    const float bias = gb[col];
    #pragma unroll
    for (int i = 0; i < 8; ++i) {
      const int row0 = m0 + wr * 128 + i * 16 + q * 4;
      #pragma unroll
      for (int t = 0; t < 4; ++t)
        fall[(size_t)(row0 + t) * 512 + col] = acc[i][j][t] + bias;
    }
  }
}

// ---------------- normalize rows of f_all (512) -> bf16 fn_all ----------------
__global__ __launch_bounds__(256) void k_norm(const float* __restrict__ fall,
                                              unsigned short* __restrict__ fn) {
  const int row = blockIdx.x * 4 + (threadIdx.x >> 6);
  const int lane = threadIdx.x & 63;
  const float4* p = (const float4*)(fall + (size_t)row * 512) + lane * 2;
  const float4 v0 = p[0], v1 = p[1];
  float ss = v0.x * v0.x + v0.y * v0.y + v0.z * v0.z + v0.w * v0.w
           + v1.x * v1.x + v1.y * v1.y + v1.z * v1.z + v1.w * v1.w;
  #pragma unroll
  for (int o = 32; o; o >>= 1) ss += __shfl_xor(ss, o, 64);
  const float sc = 1.0f / fmaxf(sqrtf(ss), 1e-12f);
  ushort4 o0, o1;
  o0.x = f2bf(v0.x * sc); o0.y = f2bf(v0.y * sc); o0.z = f2bf(v0.z * sc); o0.w = f2bf(v0.w * sc);
  o1.x = f2bf(v1.x * sc); o1.y = f2bf(v1.y * sc); o1.z = f2bf(v1.z * sc); o1.w = f2bf(v1.w * sc);
  ushort4* qo = (ushort4*)(fn + (size_t)row * 512) + lane * 2;
  qo[0] = o0; qo[1] = o1;
}

// ================= k_fused: 32x32x16 MFMA, K-quarter staging, uniform vmcnt(6) =================
// LDS (shorts): buf0 @0, buf1 @32768; each buf: Aq0..3 @ p*4096, Bq0..3 @ 16384+p*4096
// (quarter = [256 rows][16 k] bf16 = 8 KB, naturally conflict-free). excT tile @65536.
#define BUFSZ 32768
#define EXL 65536

// stage one quarter: 512 threads x 16B; thread: row = tid>>1, k-half = tid&1; dest linear.
__device__ __forceinline__ void stage_q(const unsigned short* __restrict__ src,
                                        unsigned short* smem, int dsoff, int tid) {
  const unsigned short* g = src + (size_t)(tid >> 1) * 512 + (tid & 1) * 8;
  __builtin_amdgcn_global_load_lds(
      (const __attribute__((address_space(1))) unsigned int*)g,
      (__attribute__((address_space(3))) unsigned int*)(smem + dsoff + tid * 8), 16, 0, 0);
}

__device__ __forceinline__ void stage_exc(const unsigned short* __restrict__ excTg, int c0,
                                          unsigned short* smem, int tid) {
  const int row = tid >> 5, b = tid & 31;
  const int sb = ((b & 24) | ((b ^ (row & 7)) & 7)) << 3;
  const unsigned short* g = excTg + (size_t)row * 16384 + c0 + sb;
  __builtin_amdgcn_global_load_lds(
      (const __attribute__((address_space(1))) unsigned int*)g,
      (__attribute__((address_space(3))) unsigned int*)(smem + EXL + tid * 8), 16, 0, 0);
  __builtin_amdgcn_global_load_lds(
      (const __attribute__((address_space(1))) unsigned int*)(g + 16 * 16384),
      (__attribute__((address_space(3))) unsigned int*)(smem + EXL + 4096 + tid * 8), 16, 0, 0);
}

// one phase p: 6 ds_read_b128 + 8 MFMA(32x32x16); all frags consumed in-phase
template<int P>
__device__ __forceinline__ void mma_phase32(const unsigned short* smem, int bufR,
                                            int wr, int wc, int l31, int hs8, f32x16 acc[4][2]) {
  const unsigned short* Aq = smem + bufR + P * 4096;
  const unsigned short* Bq = smem + bufR + 16384 + P * 4096;
  const s16x8 bf0 = *(const s16x8*)(Bq + (wc * 64 + l31) * 16 + hs8);
  const s16x8 bf1 = *(const s16x8*)(Bq + (wc * 64 + 32 + l31) * 16 + hs8);
  #pragma unroll
  for (int rt = 0; rt < 4; ++rt) {
    const s16x8 af = *(const s16x8*)(Aq + (wr * 128 + rt * 32 + l31) * 16 + hs8);
    acc[rt][0] = MFMA32(af, bf0, acc[rt][0]);
    acc[rt][1] = MFMA32(af, bf1, acc[rt][1]);
  }
}

#define STAGE_PAIR(P)                                                     \
  do {                                                                    \
    stage_q(An + (P) * 16, smem, bufW + (P) * 4096, tid);                 \
    stage_q(Bn + (P) * 16, smem, bufW + 16384 + (P) * 4096, tid);         \
  } while (0)

__global__ __launch_bounds__(512, 2) void k_fused(const unsigned short* __restrict__ fnall,
                                                  const unsigned short* __restrict__ excT,
                                                  float* __restrict__ partial) {
  __shared__ __align__(16) unsigned short smem[73728];  // 144 KB
  const int tid = threadIdx.x, w = tid >> 6, lane = tid & 63;
  const int wr = w >> 2, wc = w & 3;
  const int l31 = lane & 31, hs = lane >> 5, hs8 = hs * 8;
  const int r = lane & 15, q = lane >> 4, rx = r & 7;       // echo/epilogue decomposition
  const int r0 = blockIdx.x * 256;     // 32 M-tiles
  const int nchunk = blockIdx.y;       // 16 chunks x 4 j-tiles of 256
  const unsigned short* Abase = fnall + (size_t)r0 * 512;
  const unsigned short* Ebase = fnall + (size_t)8192 * 512;
  unsigned short* aLb = smem + BUFSZ;  // echo scratch = buf1 (free at echo time)

  f32x16 acc[4][2];                    // [row-tile][col-tile] 32x32 frags
  f32x4 eacc[2][2];
  #pragma unroll
  for (int a = 0; a < 2; ++a)
    #pragma unroll
    for (int b = 0; b < 2; ++b) eacc[a][b] = {0.f, 0.f, 0.f, 0.f};

  // prologue: kt=0 -> buf0, quarter order Aq0,Bq0,..,Aq3,Bq3 (matches per-phase FIFO)
  {
    const unsigned short* An = Abase;
    const unsigned short* Bn = Ebase + (size_t)(nchunk * 4) * 256 * 512;
    const int bufW = 0;
    STAGE_PAIR(0); STAGE_PAIR(1); STAGE_PAIR(2); STAGE_PAIR(3);
  }

  for (int jt = 0; jt < 4; ++jt) {
    #pragma unroll
    for (int rt = 0; rt < 4; ++rt)
      #pragma unroll
      for (int ct = 0; ct < 2; ++ct)
        #pragma unroll
        for (int e = 0; e < 16; ++e) acc[rt][ct][e] = 0.f;

    for (int tk = 0; tk < 7; ++tk) {     // steady: stage quarter p of kt+1 during phase p
      const int kt = jt * 8 + tk;
      const int bufR = (kt & 1) * BUFSZ, bufW = bufR ^ BUFSZ;
      const int kn = kt + 1;
      const unsigned short* An = Abase + (kn & 7) * 64;
      const unsigned short* Bn = Ebase + (size_t)((nchunk * 4 + (kn >> 3)) * 256) * 512 + (kn & 7) * 64;
      PHASE_SYNC(6); STAGE_PAIR(0);
      SP1(); mma_phase32<0>(smem, bufR, wr, wc, l31, hs8, acc); SP0();
      PHASE_SYNC(6); STAGE_PAIR(1);
      SP1(); mma_phase32<1>(smem, bufR, wr, wc, l31, hs8, acc); SP0();
      PHASE_SYNC(6); STAGE_PAIR(2);
      SP1(); mma_phase32<2>(smem, bufR, wr, wc, l31, hs8, acc); SP0();
      PHASE_SYNC(6); STAGE_PAIR(3);
      SP1(); mma_phase32<3>(smem, bufR, wr, wc, l31, hs8, acc); SP0();
    }
    {                                    // tk == 7: exc tile + (jt<3) next-jt K-tile 0
      const int bufR = BUFSZ, bufW = 0;  // kt odd
      const int c0e = (nchunk * 4 + jt) * 256;
      const unsigned short* An = Abase;  // kn = jt*8+8 -> (kn&7)=0
      const unsigned short* Bn = Ebase + (size_t)((nchunk * 4 + jt + 1) * 256) * 512;  // used only if jt<3
      if (jt < 3) {
        PHASE_SYNC(6); stage_exc(excT, c0e, smem, tid); STAGE_PAIR(0);
        SP1(); mma_phase32<0>(smem, bufR, wr, wc, l31, hs8, acc); SP0();
        PHASE_SYNC(8); STAGE_PAIR(1);
        SP1(); mma_phase32<1>(smem, bufR, wr, wc, l31, hs8, acc); SP0();
        PHASE_SYNC(8); STAGE_PAIR(2);
        SP1(); mma_phase32<2>(smem, bufR, wr, wc, l31, hs8, acc); SP0();
        PHASE_SYNC(8); STAGE_PAIR(3);
        SP1(); mma_phase32<3>(smem, bufR, wr, wc, l31, hs8, acc); SP0();
      } else {
        PHASE_SYNC(6); stage_exc(excT, c0e, smem, tid);
        SP1(); mma_phase32<0>(smem, bufR, wr, wc, l31, hs8, acc); SP0();
        PHASE_SYNC(6);
        SP1(); mma_phase32<1>(smem, bufR, wr, wc, l31, hs8, acc); SP0();
        PHASE_SYNC(4);
        SP1(); mma_phase32<2>(smem, bufR, wr, wc, l31, hs8, acc); SP0();
        PHASE_SYNC(2);
        SP1(); mma_phase32<3>(smem, bufR, wr, wc, l31, hs8, acc); SP0();
      }
    }

    // ---- echo: a = s^3 via aL (=buf1, free), MFMA vs excT-lds; 2 row-halves of 128
    SCHED_FENCE(); WAIT_LGKM();
    if (jt < 3) { WAIT_VM(8); } else { WAIT_VM(0); }  // excT landed; next-jt stages in flight
    BAR(); SCHED_FENCE();
    const int c0 = (nchunk * 4 + jt) * 256;
    (void)c0;
    #pragma unroll
    for (int h = 0; h < 2; ++h) {
      if (wr == h) {                     // cube-write own rows (32x32 C-layout)
        #pragma unroll
        for (int rt = 0; rt < 4; ++rt)
          #pragma unroll
          for (int ct = 0; ct < 2; ++ct)
            #pragma unroll
            for (int e = 0; e < 16; ++e) {
              const int rh = rt * 32 + (e & 3) + 8 * (e >> 2) + 4 * hs;
              const int c = wc * 64 + ct * 32 + l31;
              const int cb = c >> 3, cl = c & 7;
              const float v = acc[rt][ct][e];
              aLb[rh * 256 + ((((cb & 24) | ((cb ^ (rh & 7)) & 7)) << 3) | cl)] = f2bf(v * v * v);
            }
      }
      SCHED_FENCE(); WAIT_LGKM(); BAR(); SCHED_FENCE();
      // echo MFMA (16x16x32): wave w owns rows w*16..+15 of this half; K=256, N=32
      {
        const int rE = w * 16 + r;
        const int re8 = rE & 7;
        #pragma unroll
        for (int kc = 0; kc < 8; ++kc) {
          const int kb = kc * 4 + q;
          const s16x8 af = *(const s16x8*)(aLb + rE * 256 + (((kb & 24) | ((kb ^ re8) & 7)) << 3));
          #pragma unroll
          for (int nj = 0; nj < 2; ++nj) {
            const s16x8 bfr = *(const s16x8*)(smem + EXL + (nj * 16 + r) * 256 +
                                              (((kb & 24) | ((kb ^ rx) & 7)) << 3));
            eacc[h][nj] = MFMA16(af, bfr, eacc[h][nj]);
          }
        }
      }
      SCHED_FENCE(); WAIT_LGKM(); BAR(); SCHED_FENCE();
    }
  }

  // write partial [nchunk][8192][32]
  #pragma unroll
  for (int h = 0; h < 2; ++h)
    #pragma unroll
    for (int nj = 0; nj < 2; ++nj) {
      const int rb = r0 + h * 128 + w * 16 + q * 4;
      const int cls = nj * 16 + r;
      #pragma unroll
      for (int t = 0; t < 4; ++t)
        partial[((size_t)nchunk * 8192 + rb + t) * 32 + cls] = eacc[h][nj][t];
    }
}

// ---------------- reduce 16 partials, /b, clip ----------------
__global__ void k_reduce(const float* __restrict__ partial, const float* __restrict__ bvec,
                         float* __restrict__ out) {
  const int idx = blockIdx.x * 256 + threadIdx.x;  // 229376 total
  const int row = idx / 28, c = idx - row * 28;
  float s = 0.f;
  #pragma unroll
  for (int nc = 0; nc < 16; ++nc) s += partial[((size_t)nc * 8192 + row) * 32 + c];
  out[idx] = fminf(fmaxf(s / bvec[c], 0.f), 1.f);
}

extern "C" void kernel_launch(void* const* d_in, const int* in_sizes, int n_in,
                              void* d_out, int out_size, void* d_ws, size_t ws_size,
                              hipStream_t stream) {
  const float* features    = (const float*)d_in[0];  // [8192,1024]
  const float* ex_features = (const float*)d_in[1];  // [16384,1024]
  const float* g_w         = (const float*)d_in[2];  // [512,1024]
  const float* g_b         = (const float*)d_in[3];  // [512]
  const float* ex_classes  = (const float*)d_in[4];  // [16384,28]
  float* out = (float*)d_out;
  char* ws = (char*)d_ws;

  unsigned short* featbf = (unsigned short*)(ws + 0);
  unsigned short* exbf   = (unsigned short*)(ws + 16777216);
  unsigned short* fnall  = (unsigned short*)(ws + 0);
  float* fall            = (float*)(ws + 50331648);
  float* partial         = (float*)(ws + 50331648);
  unsigned short* gwbf   = (unsigned short*)(ws + 100663296);
  unsigned short* excT   = (unsigned short*)(ws + 101711872);
  float* bvec            = (float*)(ws + 102760448);

  k_cast_bf16<<<2048, 256, 0, stream>>>(features, featbf, 8192 * 1024 / 4);
  k_cast_bf16<<<2048, 256, 0, stream>>>(ex_features, exbf, 16384 * 1024 / 4);
  k_cast_bf16<<<512, 256, 0, stream>>>(g_w, gwbf, 512 * 1024 / 4);
  k_excT<<<32, 256, 0, stream>>>(ex_classes, excT, bvec);
  k_proj<<<dim3(96, 4), 512, 0, stream>>>(featbf, exbf, gwbf, g_b, fall);
  k_norm<<<6144, 256, 0, stream>>>(fall, fnall);
  k_fused<<<dim3(32, 16), 512, 0, stream>>>(fnall, excT, partial);
  k_reduce<<<896, 256, 0, stream>>>(partial, bvec, out);
}

// Round 12
// 250.236 us; speedup vs baseline: 3.7876x; 3.7876x over previous
//
#include <hip/hip_runtime.h>
#include <stdint.h>

typedef __attribute__((ext_vector_type(4))) float f32x4;
typedef __attribute__((ext_vector_type(8))) short s16x8;

#define MFMA16(A, B, C) __builtin_amdgcn_mfma_f32_16x16x32_bf16(A, B, C, 0, 0, 0)
#define WAIT_VM(N) asm volatile("s_waitcnt vmcnt(" #N ")" ::: "memory")
#define WAIT_LGKM() asm volatile("s_waitcnt lgkmcnt(0)" ::: "memory")
#define BAR() __builtin_amdgcn_s_barrier()
#define SCHED_FENCE() __builtin_amdgcn_sched_barrier(0)
#define SP1() __builtin_amdgcn_s_setprio(1)
#define SP0() __builtin_amdgcn_s_setprio(0)

__device__ __forceinline__ unsigned short f2bf(float x) {
  union { float f; unsigned u; } v; v.f = x;
  return (unsigned short)((v.u + 0x7fffu + ((v.u >> 16) & 1u)) >> 16);
}

// ---------------- cast f32 -> bf16, 4 elems/thread ----------------
__global__ void k_cast_bf16(const float* __restrict__ in, unsigned short* __restrict__ out, int n4) {
  int i = blockIdx.x * blockDim.x + threadIdx.x;
  const int stride = gridDim.x * blockDim.x;
  for (; i < n4; i += stride) {
    const float4 v = ((const float4*)in)[i];
    ushort4 o;
    o.x = f2bf(v.x); o.y = f2bf(v.y); o.z = f2bf(v.z); o.w = f2bf(v.w);
    ((ushort4*)out)[i] = o;
  }
}

// ---------------- exc [16384][28] -> excT bf16 [32][16384] (rows 28..31 = 0) + b[28] ----------------
__global__ void k_excT(const float* __restrict__ exc, unsigned short* __restrict__ excT,
                       float* __restrict__ bvec) {
  const int c = blockIdx.x;        // 0..31
  const int tid = threadIdx.x;     // 256
  float sum = 0.f;
  for (int j = tid; j < 16384; j += 256) {
    const float v = (c < 28) ? exc[(size_t)j * 28 + c] : 0.f;
    excT[(size_t)c * 16384 + j] = f2bf(v);
    sum += v;
  }
  #pragma unroll
  for (int o = 32; o; o >>= 1) sum += __shfl_down(sum, o, 64);
  __shared__ float wsum[4];
  if ((tid & 63) == 0) wsum[tid >> 6] = sum;
  __syncthreads();
  if (tid == 0 && c < 28) bvec[c] = fmaxf(wsum[0] + wsum[1] + wsum[2] + wsum[3], 1.0f);
}

// ================= k_proj (unchanged working engine) =================
__device__ __forceinline__ void stage_a(const unsigned short* __restrict__ src, int ld,
                                        unsigned short* smem, int dsoff, int w, int offsrc) {
  #pragma unroll
  for (int c = 0; c < 4; ++c)
    __builtin_amdgcn_global_load_lds(
        (const __attribute__((address_space(1))) unsigned int*)(src + offsrc + c * 64 * ld),
        (__attribute__((address_space(3))) unsigned int*)(smem + dsoff + c * 4096 + w * 512),
        16, 0, 0);
}
__device__ __forceinline__ void stage_b(const unsigned short* __restrict__ src, int ld,
                                        unsigned short* smem, int dsoff, int w, int offsrc) {
  #pragma unroll
  for (int c = 0; c < 2; ++c)
    __builtin_amdgcn_global_load_lds(
        (const __attribute__((address_space(1))) unsigned int*)(src + offsrc + c * 64 * ld),
        (__attribute__((address_space(3))) unsigned int*)(smem + dsoff + c * 4096 + w * 512),
        16, 0, 0);
}

__device__ __forceinline__ void mma_step_p(const unsigned short* smem, int ao, int bo,
                                           int wr, int wc, int r, int q, f32x4 acc[8][2]) {
  const int rx = r & 7;
  #pragma unroll
  for (int ks = 0; ks < 2; ++ks) {
    const int sb = ((ks * 4 + q) ^ rx) << 3;
    s16x8 bf[2];
    #pragma unroll
    for (int j = 0; j < 2; ++j)
      bf[j] = *(const s16x8*)(smem + bo + (wc * 32 + j * 16 + r) * 64 + sb);
    #pragma unroll
    for (int i = 0; i < 8; ++i) {
      const s16x8 af = *(const s16x8*)(smem + ao + (wr * 128 + i * 16 + r) * 64 + sb);
      #pragma unroll
      for (int j = 0; j < 2; ++j)
        acc[i][j] = MFMA16(af, bf[j], acc[i][j]);
    }
  }
}

#define PA0 0
#define PB0 16384
#define PA1 24576
#define PB1 40960

__global__ __launch_bounds__(512, 2) void k_proj(const unsigned short* __restrict__ featbf,
                                                 const unsigned short* __restrict__ exbf,
                                                 const unsigned short* __restrict__ gwbf,
                                                 const float* __restrict__ gb,
                                                 float* __restrict__ fall) {
  __shared__ __align__(16) unsigned short smem[49152];  // 96 KB
  const int tid = threadIdx.x, w = tid >> 6, lane = tid & 63;
  const int wr = w >> 2, wc = w & 3, r = lane & 15, q = lane >> 4;
  const int offsrc = (w * 8 + (lane >> 3)) * 1024 + (((lane & 7) ^ (lane >> 3)) << 3);
  const int m0 = blockIdx.x * 256;
  const int n0 = blockIdx.y * 128;
  const unsigned short* Asrc = (m0 < 8192) ? (featbf + (size_t)m0 * 1024)
                                           : (exbf + (size_t)(m0 - 8192) * 1024);
  const unsigned short* Bsrc = gwbf + (size_t)n0 * 1024;
  f32x4 acc[8][2];
  #pragma unroll
  for (int i = 0; i < 8; ++i)
    #pragma unroll
    for (int j = 0; j < 2; ++j) acc[i][j] = {0.f, 0.f, 0.f, 0.f};

  stage_a(Asrc, 1024, smem, PA0, w, offsrc);
  stage_b(Bsrc, 1024, smem, PB0, w, offsrc);
  for (int t = 0; t < 15; ++t) {
    const int na = ((t + 1) & 1) ? PA1 : PA0, nbb = ((t + 1) & 1) ? PB1 : PB0;
    stage_a(Asrc + (t + 1) * 64, 1024, smem, na, w, offsrc);
    stage_b(Bsrc + (t + 1) * 64, 1024, smem, nbb, w, offsrc);
    WAIT_VM(6);
    BAR();
    mma_step_p(smem, (t & 1) ? PA1 : PA0, (t & 1) ? PB1 : PB0, wr, wc, r, q, acc);
    WAIT_LGKM();
    BAR();
  }
  WAIT_VM(0);
  BAR();
  mma_step_p(smem, PA1, PB1, wr, wc, r, q, acc);

  #pragma unroll
  for (int j = 0; j < 2; ++j) {
    const int col = n0 + wc * 32 + j * 16 + r;
    const float bias = gb[col];
    #pragma unroll
    for (int i = 0; i < 8; ++i) {
      const int row0 = m0 + wr * 128 + i * 16 + q * 4;
      #pragma unroll
      for (int t = 0; t < 4; ++t)
        fall[(size_t)(row0 + t) * 512 + col] = acc[i][j][t] + bias;
    }
  }
}

// ---------------- normalize rows of f_all (512) -> bf16 fn_all ----------------
__global__ __launch_bounds__(256) void k_norm(const float* __restrict__ fall,
                                              unsigned short* __restrict__ fn) {
  const int row = blockIdx.x * 4 + (threadIdx.x >> 6);
  const int lane = threadIdx.x & 63;
  const float4* p = (const float4*)(fall + (size_t)row * 512) + lane * 2;
  const float4 v0 = p[0], v1 = p[1];
  float ss = v0.x * v0.x + v0.y * v0.y + v0.z * v0.z + v0.w * v0.w
           + v1.x * v1.x + v1.y * v1.y + v1.z * v1.z + v1.w * v1.w;
  #pragma unroll
  for (int o = 32; o; o >>= 1) ss += __shfl_xor(ss, o, 64);
  const float sc = 1.0f / fmaxf(sqrtf(ss), 1e-12f);
  ushort4 o0, o1;
  o0.x = f2bf(v0.x * sc); o0.y = f2bf(v0.y * sc); o0.z = f2bf(v0.z * sc); o0.w = f2bf(v0.w * sc);
  o1.x = f2bf(v1.x * sc); o1.y = f2bf(v1.y * sc); o1.z = f2bf(v1.z * sc); o1.w = f2bf(v1.w * sc);
  ushort4* qo = (ushort4*)(fn + (size_t)row * 512) + lane * 2;
  qo[0] = o0; qo[1] = o1;
}

// ================= k_fused: BK=32, ONE barrier/K-tile, separate aL =================
// LDS (shorts): buf0 @0, buf1 @16384 (each: A[256][32] @0 | B[256][32] @8192),
// excT [32][256] @32768, aL [128][256] @40960. Total 73728 shorts = 144 KB.
#define BUF 16384
#define EXLo 32768
#define ALo 40960

// stage one 128x32 piece (1 gload/thread): row = tid>>2, blk = tid&3; linear, conflict-free.
__device__ __forceinline__ void stage_p(const unsigned short* __restrict__ src,
                                        unsigned short* smem, int dsoff, int tid) {
  const unsigned short* g = src + (size_t)(tid >> 2) * 512 + (tid & 3) * 8;
  __builtin_amdgcn_global_load_lds(
      (const __attribute__((address_space(1))) unsigned int*)g,
      (__attribute__((address_space(3))) unsigned int*)(smem + dsoff + tid * 8), 16, 0, 0);
}

__device__ __forceinline__ void stage_exc(const unsigned short* __restrict__ excTg, int c0,
                                          unsigned short* smem, int tid) {
  const int row = tid >> 5, b = tid & 31;
  const int sb = ((b & 24) | ((b ^ (row & 7)) & 7)) << 3;
  const unsigned short* g = excTg + (size_t)row * 16384 + c0 + sb;
  __builtin_amdgcn_global_load_lds(
      (const __attribute__((address_space(1))) unsigned int*)g,
      (__attribute__((address_space(3))) unsigned int*)(smem + EXLo + tid * 8), 16, 0, 0);
  __builtin_amdgcn_global_load_lds(
      (const __attribute__((address_space(1))) unsigned int*)(g + 16 * 16384),
      (__attribute__((address_space(3))) unsigned int*)(smem + EXLo + 4096 + tid * 8), 16, 0, 0);
}

// one K-tile (BK=32): 12 ds_read_b128 + 32 MFMA; B read once (held in-tile only)
__device__ __forceinline__ void ktile32(const unsigned short* smem, int bufR,
                                        int wr, int wc, int r, int q, f32x4 acc[2][2][4][2]) {
  const int koff = q * 8;
  const unsigned short* Bb = smem + bufR + 8192 + (wc * 32 + r) * 32 + koff;
  s16x8 bf[2][2];
  #pragma unroll
  for (int nh = 0; nh < 2; ++nh)
    #pragma unroll
    for (int fj = 0; fj < 2; ++fj)
      bf[nh][fj] = *(const s16x8*)(Bb + (nh * 128 + fj * 16) * 32);
  #pragma unroll
  for (int MH = 0; MH < 2; ++MH) {
    const unsigned short* Ab = smem + bufR + (MH * 128 + wr * 64 + r) * 32 + koff;
    #pragma unroll
    for (int fi = 0; fi < 4; ++fi) {
      const s16x8 af = *(const s16x8*)(Ab + fi * 512);
      #pragma unroll
      for (int nh = 0; nh < 2; ++nh)
        #pragma unroll
        for (int fj = 0; fj < 2; ++fj)
          acc[MH][nh][fi][fj] = MFMA16(af, bf[nh][fj], acc[MH][nh][fi][fj]);
    }
  }
}

__global__ __launch_bounds__(512, 2) void k_fused(const unsigned short* __restrict__ fnall,
                                                  const unsigned short* __restrict__ excT,
                                                  float* __restrict__ partial) {
  __shared__ __align__(16) unsigned short smem[73728];  // 144 KB
  const int tid = threadIdx.x, w = tid >> 6, lane = tid & 63;
  const int wr = w >> 2, wc = w & 3, r = lane & 15, q = lane >> 4, rx = r & 7;
  const int r0 = blockIdx.x * 256;     // 32 M-tiles
  const int nchunk = blockIdx.y;       // 16 chunks x 4 j-tiles of 256
  const unsigned short* Abase = fnall + (size_t)r0 * 512;
  const unsigned short* Ebase = fnall + (size_t)8192 * 512;
  unsigned short* aLb = smem + ALo;

  f32x4 acc[2][2][4][2];               // [MH][NH][fi][fj]
  f32x4 eacc[2][2];
  #pragma unroll
  for (int a = 0; a < 2; ++a)
    #pragma unroll
    for (int b = 0; b < 2; ++b) eacc[a][b] = {0.f, 0.f, 0.f, 0.f};

  // prologue: jt0 tile0 -> buf0 (order B0,B1,A0,A1)
  {
    const unsigned short* Bp = Ebase + (size_t)(nchunk * 4) * 256 * 512;
    stage_p(Bp, smem, 8192, tid);
    stage_p(Bp + 128 * 512, smem, 12288, tid);
    stage_p(Abase, smem, 0, tid);
    stage_p(Abase + 128 * 512, smem, 4096, tid);
  }

  for (int jt = 0; jt < 4; ++jt) {
    const int c0 = (nchunk * 4 + jt) * 256;
    const unsigned short* Bsrc = Ebase + (size_t)c0 * 512;
    #pragma unroll
    for (int a = 0; a < 2; ++a)
      #pragma unroll
      for (int b = 0; b < 2; ++b)
        #pragma unroll
        for (int fi = 0; fi < 4; ++fi)
          #pragma unroll
          for (int fj = 0; fj < 2; ++fj) acc[a][b][fi][fj] = {0.f, 0.f, 0.f, 0.f};

    for (int tk = 0; tk < 16; ++tk) {
      const int bufR = (tk & 1) * BUF, bufW = bufR ^ BUF;
      // single per-tile sync: own ds reads drained; ALL waves' tile-t pieces landed
      SCHED_FENCE(); WAIT_LGKM(); WAIT_VM(0); BAR(); SCHED_FENCE();
      if (tk < 15) {
        const unsigned short* An = Abase + (tk + 1) * 32;
        const unsigned short* Bn = Bsrc + (tk + 1) * 32;
        stage_p(Bn, smem, bufW + 8192, tid);
        stage_p(Bn + 128 * 512, smem, bufW + 12288, tid);
        stage_p(An, smem, bufW + 0, tid);
        stage_p(An + 128 * 512, smem, bufW + 4096, tid);
      } else {
        stage_exc(excT, c0, smem, tid);          // exc first (echo waits vm(4))
        if (jt < 3) {
          const unsigned short* Bn = Ebase + (size_t)(c0 + 256) * 512;
          stage_p(Bn, smem, bufW + 8192, tid);
          stage_p(Bn + 128 * 512, smem, bufW + 12288, tid);
          stage_p(Abase, smem, bufW + 0, tid);
          stage_p(Abase + 128 * 512, smem, bufW + 4096, tid);
        }
      }
      SP1(); ktile32(smem, bufR, wr, wc, r, q, acc); SP0();
    }

    // ---- echo: a = s^3 via aL (separate region), MFMA vs excT-lds; 2 row-halves of 128
    SCHED_FENCE(); WAIT_LGKM();
    if (jt < 3) { WAIT_VM(4); } else { WAIT_VM(0); }  // exc landed; next-jt pieces keep flying
    BAR(); SCHED_FENCE();
    #pragma unroll
    for (int h = 0; h < 2; ++h) {
      // ALL waves cube-write their acc[h] quadrants of half h (aL rows wr*64..wr*64+63)
      #pragma unroll
      for (int nh = 0; nh < 2; ++nh)
        #pragma unroll
        for (int fi = 0; fi < 4; ++fi)
          #pragma unroll
          for (int fj = 0; fj < 2; ++fj) {
            const int colc = nh * 128 + wc * 32 + fj * 16 + r;
            const int cb = colc >> 3, cl = colc & 7;
            #pragma unroll
            for (int t2 = 0; t2 < 4; ++t2) {
              const int row = wr * 64 + fi * 16 + q * 4 + t2;
              const float v = acc[h][nh][fi][fj][t2];
              aLb[row * 256 + ((((cb & 24) | ((cb ^ (row & 7)) & 7)) << 3) | cl)] = f2bf(v * v * v);
            }
          }
      SCHED_FENCE(); WAIT_LGKM(); BAR(); SCHED_FENCE();
      // echo MFMA (16x16x32): wave w owns rows w*16..+15 of this half; K=256, N=32
      {
        const int rE = w * 16 + r;
        const int re8 = rE & 7;
        #pragma unroll
        for (int kc = 0; kc < 8; ++kc) {
          const int kb = kc * 4 + q;
          const s16x8 af = *(const s16x8*)(aLb + rE * 256 + (((kb & 24) | ((kb ^ re8) & 7)) << 3));
          #pragma unroll
          for (int nj = 0; nj < 2; ++nj) {
            const s16x8 bfr = *(const s16x8*)(smem + EXLo + (nj * 16 + r) * 256 +
                                              (((kb & 24) | ((kb ^ rx) & 7)) << 3));
            eacc[h][nj] = MFMA16(af, bfr, eacc[h][nj]);
          }
        }
      }
      SCHED_FENCE(); WAIT_LGKM(); BAR(); SCHED_FENCE();
    }
  }

  // write partial [nchunk][8192][32]
  #pragma unroll
  for (int h = 0; h < 2; ++h)
    #pragma unroll
    for (int nj = 0; nj < 2; ++nj) {
      const int rb = r0 + h * 128 + w * 16 + q * 4;
      const int cls = nj * 16 + r;
      #pragma unroll
      for (int t = 0; t < 4; ++t)
        partial[((size_t)nchunk * 8192 + rb + t) * 32 + cls] = eacc[h][nj][t];
    }
}

// ---------------- reduce 16 partials, /b, clip ----------------
__global__ void k_reduce(const float* __restrict__ partial, const float* __restrict__ bvec,
                         float* __restrict__ out) {
  const int idx = blockIdx.x * 256 + threadIdx.x;  // 229376 total
  const int row = idx / 28, c = idx - row * 28;
  float s = 0.f;
  #pragma unroll
  for (int nc = 0; nc < 16; ++nc) s += partial[((size_t)nc * 8192 + row) * 32 + c];
  out[idx] = fminf(fmaxf(s / bvec[c], 0.f), 1.f);
}

extern "C" void kernel_launch(void* const* d_in, const int* in_sizes, int n_in,
                              void* d_out, int out_size, void* d_ws, size_t ws_size,
                              hipStream_t stream) {
  const float* features    = (const float*)d_in[0];  // [8192,1024]
  const float* ex_features = (const float*)d_in[1];  // [16384,1024]
  const float* g_w         = (const float*)d_in[2];  // [512,1024]
  const float* g_b         = (const float*)d_in[3];  // [512]
  const float* ex_classes  = (const float*)d_in[4];  // [16384,28]
  float* out = (float*)d_out;
  char* ws = (char*)d_ws;

  unsigned short* featbf = (unsigned short*)(ws + 0);
  unsigned short* exbf   = (unsigned short*)(ws + 16777216);
  unsigned short* fnall  = (unsigned short*)(ws + 0);
  float* fall            = (float*)(ws + 50331648);
  float* partial         = (float*)(ws + 50331648);
  unsigned short* gwbf   = (unsigned short*)(ws + 100663296);
  unsigned short* excT   = (unsigned short*)(ws + 101711872);
  float* bvec            = (float*)(ws + 102760448);

  k_cast_bf16<<<2048, 256, 0, stream>>>(features, featbf, 8192 * 1024 / 4);
  k_cast_bf16<<<2048, 256, 0, stream>>>(ex_features, exbf, 16384 * 1024 / 4);
  k_cast_bf16<<<512, 256, 0, stream>>>(g_w, gwbf, 512 * 1024 / 4);
  k_excT<<<32, 256, 0, stream>>>(ex_classes, excT, bvec);
  k_proj<<<dim3(96, 4), 512, 0, stream>>>(featbf, exbf, gwbf, g_b, fall);
  k_norm<<<6144, 256, 0, stream>>>(fall, fnall);
  k_fused<<<dim3(32, 16), 512, 0, stream>>>(fnall, excT, partial);
  k_reduce<<<896, 256, 0, stream>>>(partial, bvec, out);
}

// Round 13
// 245.242 us; speedup vs baseline: 3.8648x; 1.0204x over previous
//
#include <hip/hip_runtime.h>
#include <stdint.h>

typedef __attribute__((ext_vector_type(4))) float f32x4;
typedef __attribute__((ext_vector_type(8))) short s16x8;

#define MFMA16(A, B, C) __builtin_amdgcn_mfma_f32_16x16x32_bf16(A, B, C, 0, 0, 0)
#define WAIT_VM(N) asm volatile("s_waitcnt vmcnt(" #N ")" ::: "memory")
#define WAIT_LGKM() asm volatile("s_waitcnt lgkmcnt(0)" ::: "memory")
#define BAR() __builtin_amdgcn_s_barrier()
#define SCHED_FENCE() __builtin_amdgcn_sched_barrier(0)
#define SP1() __builtin_amdgcn_s_setprio(1)
#define SP0() __builtin_amdgcn_s_setprio(0)

__device__ __forceinline__ unsigned short f2bf(float x) {
  union { float f; unsigned u; } v; v.f = x;
  return (unsigned short)((v.u + 0x7fffu + ((v.u >> 16) & 1u)) >> 16);
}

// ---------------- cast f32 -> bf16, 4 elems/thread ----------------
__global__ void k_cast_bf16(const float* __restrict__ in, unsigned short* __restrict__ out, int n4) {
  int i = blockIdx.x * blockDim.x + threadIdx.x;
  const int stride = gridDim.x * blockDim.x;
  for (; i < n4; i += stride) {
    const float4 v = ((const float4*)in)[i];
    ushort4 o;
    o.x = f2bf(v.x); o.y = f2bf(v.y); o.z = f2bf(v.z); o.w = f2bf(v.w);
    ((ushort4*)out)[i] = o;
  }
}

// ---------------- exc [16384][28] -> excT bf16 [32][16384] (rows 28..31 = 0) + b[28] ----------------
__global__ void k_excT(const float* __restrict__ exc, unsigned short* __restrict__ excT,
                       float* __restrict__ bvec) {
  const int c = blockIdx.x;        // 0..31
  const int tid = threadIdx.x;     // 256
  float sum = 0.f;
  for (int j = tid; j < 16384; j += 256) {
    const float v = (c < 28) ? exc[(size_t)j * 28 + c] : 0.f;
    excT[(size_t)c * 16384 + j] = f2bf(v);
    sum += v;
  }
  #pragma unroll
  for (int o = 32; o; o >>= 1) sum += __shfl_down(sum, o, 64);
  __shared__ float wsum[4];
  if ((tid & 63) == 0) wsum[tid >> 6] = sum;
  __syncthreads();
  if (tid == 0 && c < 28) bvec[c] = fmaxf(wsum[0] + wsum[1] + wsum[2] + wsum[3], 1.0f);
}

// ================= k_proj (unchanged working engine) =================
__device__ __forceinline__ void stage_a(const unsigned short* __restrict__ src, int ld,
                                        unsigned short* smem, int dsoff, int w, int offsrc) {
  #pragma unroll
  for (int c = 0; c < 4; ++c)
    __builtin_amdgcn_global_load_lds(
        (const __attribute__((address_space(1))) unsigned int*)(src + offsrc + c * 64 * ld),
        (__attribute__((address_space(3))) unsigned int*)(smem + dsoff + c * 4096 + w * 512),
        16, 0, 0);
}
__device__ __forceinline__ void stage_b(const unsigned short* __restrict__ src, int ld,
                                        unsigned short* smem, int dsoff, int w, int offsrc) {
  #pragma unroll
  for (int c = 0; c < 2; ++c)
    __builtin_amdgcn_global_load_lds(
        (const __attribute__((address_space(1))) unsigned int*)(src + offsrc + c * 64 * ld),
        (__attribute__((address_space(3))) unsigned int*)(smem + dsoff + c * 4096 + w * 512),
        16, 0, 0);
}

__device__ __forceinline__ void mma_step_p(const unsigned short* smem, int ao, int bo,
                                           int wr, int wc, int r, int q, f32x4 acc[8][2]) {
  const int rx = r & 7;
  #pragma unroll
  for (int ks = 0; ks < 2; ++ks) {
    const int sb = ((ks * 4 + q) ^ rx) << 3;
    s16x8 bf[2];
    #pragma unroll
    for (int j = 0; j < 2; ++j)
      bf[j] = *(const s16x8*)(smem + bo + (wc * 32 + j * 16 + r) * 64 + sb);
    #pragma unroll
    for (int i = 0; i < 8; ++i) {
      const s16x8 af = *(const s16x8*)(smem + ao + (wr * 128 + i * 16 + r) * 64 + sb);
      #pragma unroll
      for (int j = 0; j < 2; ++j)
        acc[i][j] = MFMA16(af, bf[j], acc[i][j]);
    }
  }
}

#define PA0 0
#define PB0 16384
#define PA1 24576
#define PB1 40960

__global__ __launch_bounds__(512, 2) void k_proj(const unsigned short* __restrict__ featbf,
                                                 const unsigned short* __restrict__ exbf,
                                                 const unsigned short* __restrict__ gwbf,
                                                 const float* __restrict__ gb,
                                                 float* __restrict__ fall) {
  __shared__ __align__(16) unsigned short smem[49152];  // 96 KB
  const int tid = threadIdx.x, w = tid >> 6, lane = tid & 63;
  const int wr = w >> 2, wc = w & 3, r = lane & 15, q = lane >> 4;
  const int offsrc = (w * 8 + (lane >> 3)) * 1024 + (((lane & 7) ^ (lane >> 3)) << 3);
  const int m0 = blockIdx.x * 256;
  const int n0 = blockIdx.y * 128;
  const unsigned short* Asrc = (m0 < 8192) ? (featbf + (size_t)m0 * 1024)
                                           : (exbf + (size_t)(m0 - 8192) * 1024);
  const unsigned short* Bsrc = gwbf + (size_t)n0 * 1024;
  f32x4 acc[8][2];
  #pragma unroll
  for (int i = 0; i < 8; ++i)
    #pragma unroll
    for (int j = 0; j < 2; ++j) acc[i][j] = {0.f, 0.f, 0.f, 0.f};

  stage_a(Asrc, 1024, smem, PA0, w, offsrc);
  stage_b(Bsrc, 1024, smem, PB0, w, offsrc);
  for (int t = 0; t < 15; ++t) {
    const int na = ((t + 1) & 1) ? PA1 : PA0, nbb = ((t + 1) & 1) ? PB1 : PB0;
    stage_a(Asrc + (t + 1) * 64, 1024, smem, na, w, offsrc);
    stage_b(Bsrc + (t + 1) * 64, 1024, smem, nbb, w, offsrc);
    WAIT_VM(6);
    BAR();
    mma_step_p(smem, (t & 1) ? PA1 : PA0, (t & 1) ? PB1 : PB0, wr, wc, r, q, acc);
    WAIT_LGKM();
    BAR();
  }
  WAIT_VM(0);
  BAR();
  mma_step_p(smem, PA1, PB1, wr, wc, r, q, acc);

  #pragma unroll
  for (int j = 0; j < 2; ++j) {
    const int col = n0 + wc * 32 + j * 16 + r;
    const float bias = gb[col];
    #pragma unroll
    for (int i = 0; i < 8; ++i) {
      const int row0 = m0 + wr * 128 + i * 16 + q * 4;
      #pragma unroll
      for (int t = 0; t < 4; ++t)
        fall[(size_t)(row0 + t) * 512 + col] = acc[i][j][t] + bias;
    }
  }
}

// ---------------- normalize rows of f_all (512) -> bf16 fn_all ----------------
__global__ __launch_bounds__(256) void k_norm(const float* __restrict__ fall,
                                              unsigned short* __restrict__ fn) {
  const int row = blockIdx.x * 4 + (threadIdx.x >> 6);
  const int lane = threadIdx.x & 63;
  const float4* p = (const float4*)(fall + (size_t)row * 512) + lane * 2;
  const float4 v0 = p[0], v1 = p[1];
  float ss = v0.x * v0.x + v0.y * v0.y + v0.z * v0.z + v0.w * v0.w
           + v1.x * v1.x + v1.y * v1.y + v1.z * v1.z + v1.w * v1.w;
  #pragma unroll
  for (int o = 32; o; o >>= 1) ss += __shfl_xor(ss, o, 64);
  const float sc = 1.0f / fmaxf(sqrtf(ss), 1e-12f);
  ushort4 o0, o1;
  o0.x = f2bf(v0.x * sc); o0.y = f2bf(v0.y * sc); o0.z = f2bf(v0.z * sc); o0.w = f2bf(v0.w * sc);
  o1.x = f2bf(v1.x * sc); o1.y = f2bf(v1.y * sc); o1.z = f2bf(v1.z * sc); o1.w = f2bf(v1.w * sc);
  ushort4* qo = (ushort4*)(fn + (size_t)row * 512) + lane * 2;
  qo[0] = o0; qo[1] = o1;
}

// ================= k_fused: BK=32, ONE barrier/K-tile, swizzled staging =================
// LDS (shorts): buf0 @0, buf1 @16384 (each: A[256][32] @0 | B[256][32] @8192),
// excT [32][256] @32768, aL [128][256] @40960. Total 73728 shorts = 144 KB.
// Staging swizzle: LDS[row][blk] = G[row][blk ^ ((row>>1)&3)] (blk = 8-short chunk).
// Frag rows are 16k + r, so read koff = (q ^ ((r>>1)&3))*8 is lane-constant.
#define BUF 16384
#define EXLo 32768
#define ALo 40960

// stage one 128x32 piece (1 gload/thread): row = tid>>2, blk = tid&3; dest linear.
__device__ __forceinline__ void stage_p(const unsigned short* __restrict__ src,
                                        unsigned short* smem, int dsoff, int tid) {
  const int row = tid >> 2;
  const int scb = (tid & 3) ^ ((tid >> 3) & 3);  // source block = blk ^ ((row>>1)&3)
  const unsigned short* g = src + (size_t)row * 512 + scb * 8;
  __builtin_amdgcn_global_load_lds(
      (const __attribute__((address_space(1))) unsigned int*)g,
      (__attribute__((address_space(3))) unsigned int*)(smem + dsoff + tid * 8), 16, 0, 0);
}

__device__ __forceinline__ void stage_exc(const unsigned short* __restrict__ excTg, int c0,
                                          unsigned short* smem, int tid) {
  const int row = tid >> 5, b = tid & 31;
  const int sb = ((b & 24) | ((b ^ (row & 7)) & 7)) << 3;
  const unsigned short* g = excTg + (size_t)row * 16384 + c0 + sb;
  __builtin_amdgcn_global_load_lds(
      (const __attribute__((address_space(1))) unsigned int*)g,
      (__attribute__((address_space(3))) unsigned int*)(smem + EXLo + tid * 8), 16, 0, 0);
  __builtin_amdgcn_global_load_lds(
      (const __attribute__((address_space(1))) unsigned int*)(g + 16 * 16384),
      (__attribute__((address_space(3))) unsigned int*)(smem + EXLo + 4096 + tid * 8), 16, 0, 0);
}

// one K-tile (BK=32): 12 ds_read_b128 + 32 MFMA; B read once (held in-tile only)
__device__ __forceinline__ void ktile32(const unsigned short* smem, int bufR,
                                        int wr, int wc, int r, int q, int koff,
                                        f32x4 acc[2][2][4][2]) {
  const unsigned short* Bb = smem + bufR + 8192 + (wc * 32 + r) * 32 + koff;
  s16x8 bf[2][2];
  #pragma unroll
  for (int nh = 0; nh < 2; ++nh)
    #pragma unroll
    for (int fj = 0; fj < 2; ++fj)
      bf[nh][fj] = *(const s16x8*)(Bb + (nh * 128 + fj * 16) * 32);
  #pragma unroll
  for (int MH = 0; MH < 2; ++MH) {
    const unsigned short* Ab = smem + bufR + (MH * 128 + wr * 64 + r) * 32 + koff;
    #pragma unroll
    for (int fi = 0; fi < 4; ++fi) {
      const s16x8 af = *(const s16x8*)(Ab + fi * 512);
      #pragma unroll
      for (int nh = 0; nh < 2; ++nh)
        #pragma unroll
        for (int fj = 0; fj < 2; ++fj)
          acc[MH][nh][fi][fj] = MFMA16(af, bf[nh][fj], acc[MH][nh][fi][fj]);
    }
  }
}

__global__ __launch_bounds__(512, 2) void k_fused(const unsigned short* __restrict__ fnall,
                                                  const unsigned short* __restrict__ excT,
                                                  float* __restrict__ partial) {
  __shared__ __align__(16) unsigned short smem[73728];  // 144 KB
  const int tid = threadIdx.x, w = tid >> 6, lane = tid & 63;
  const int wr = w >> 2, wc = w & 3, r = lane & 15, q = lane >> 4, rx = r & 7;
  const int koff = (q ^ ((r >> 1) & 3)) << 3;  // swizzled K-chunk offset (shorts)
  const int r0 = blockIdx.x * 256;     // 32 M-tiles
  const int nchunk = blockIdx.y;       // 16 chunks x 4 j-tiles of 256
  const unsigned short* Abase = fnall + (size_t)r0 * 512;
  const unsigned short* Ebase = fnall + (size_t)8192 * 512;
  unsigned short* aLb = smem + ALo;

  f32x4 acc[2][2][4][2];               // [MH][NH][fi][fj]
  f32x4 eacc[2][2];
  #pragma unroll
  for (int a = 0; a < 2; ++a)
    #pragma unroll
    for (int b = 0; b < 2; ++b) eacc[a][b] = {0.f, 0.f, 0.f, 0.f};

  // prologue: jt0 tile0 -> buf0 (order B0,B1,A0,A1)
  {
    const unsigned short* Bp = Ebase + (size_t)(nchunk * 4) * 256 * 512;
    stage_p(Bp, smem, 8192, tid);
    stage_p(Bp + 128 * 512, smem, 12288, tid);
    stage_p(Abase, smem, 0, tid);
    stage_p(Abase + 128 * 512, smem, 4096, tid);
  }

  for (int jt = 0; jt < 4; ++jt) {
    const int c0 = (nchunk * 4 + jt) * 256;
    const unsigned short* Bsrc = Ebase + (size_t)c0 * 512;
    #pragma unroll
    for (int a = 0; a < 2; ++a)
      #pragma unroll
      for (int b = 0; b < 2; ++b)
        #pragma unroll
        for (int fi = 0; fi < 4; ++fi)
          #pragma unroll
          for (int fj = 0; fj < 2; ++fj) acc[a][b][fi][fj] = {0.f, 0.f, 0.f, 0.f};

    for (int tk = 0; tk < 16; ++tk) {
      const int bufR = (tk & 1) * BUF, bufW = bufR ^ BUF;
      // single per-tile sync: own ds reads drained; ALL waves' tile-t pieces landed
      SCHED_FENCE(); WAIT_LGKM(); WAIT_VM(0); BAR(); SCHED_FENCE();
      if (tk < 15) {
        const unsigned short* An = Abase + (tk + 1) * 32;
        const unsigned short* Bn = Bsrc + (tk + 1) * 32;
        stage_p(Bn, smem, bufW + 8192, tid);
        stage_p(Bn + 128 * 512, smem, bufW + 12288, tid);
        stage_p(An, smem, bufW + 0, tid);
        stage_p(An + 128 * 512, smem, bufW + 4096, tid);
      } else {
        stage_exc(excT, c0, smem, tid);          // exc first (echo waits vm(4))
        if (jt < 3) {
          const unsigned short* Bn = Ebase + (size_t)(c0 + 256) * 512;
          stage_p(Bn, smem, bufW + 8192, tid);
          stage_p(Bn + 128 * 512, smem, bufW + 12288, tid);
          stage_p(Abase, smem, bufW + 0, tid);
          stage_p(Abase + 128 * 512, smem, bufW + 4096, tid);
        }
      }
      SP1(); ktile32(smem, bufR, wr, wc, r, q, koff, acc); SP0();
    }

    // ---- echo: a = s^3 via aL (separate region), MFMA vs excT-lds; 2 row-halves of 128
    SCHED_FENCE(); WAIT_LGKM();
    if (jt < 3) { WAIT_VM(4); } else { WAIT_VM(0); }  // exc landed; next-jt pieces keep flying
    BAR(); SCHED_FENCE();
    #pragma unroll
    for (int h = 0; h < 2; ++h) {
      // ALL waves cube-write their acc[h] quadrants of half h (aL rows wr*64..wr*64+63)
      #pragma unroll
      for (int nh = 0; nh < 2; ++nh)
        #pragma unroll
        for (int fi = 0; fi < 4; ++fi)
          #pragma unroll
          for (int fj = 0; fj < 2; ++fj) {
            const int colc = nh * 128 + wc * 32 + fj * 16 + r;
            const int cb = colc >> 3, cl = colc & 7;
            #pragma unroll
            for (int t2 = 0; t2 < 4; ++t2) {
              const int row = wr * 64 + fi * 16 + q * 4 + t2;
              const float v = acc[h][nh][fi][fj][t2];
              aLb[row * 256 + ((((cb & 24) | ((cb ^ (row & 7)) & 7)) << 3) | cl)] = f2bf(v * v * v);
            }
          }
      SCHED_FENCE(); WAIT_LGKM(); BAR(); SCHED_FENCE();
      // echo MFMA (16x16x32): wave w owns rows w*16..+15 of this half; K=256, N=32
      {
        const int rE = w * 16 + r;
        const int re8 = rE & 7;
        #pragma unroll
        for (int kc = 0; kc < 8; ++kc) {
          const int kb = kc * 4 + q;
          const s16x8 af = *(const s16x8*)(aLb + rE * 256 + (((kb & 24) | ((kb ^ re8) & 7)) << 3));
          #pragma unroll
          for (int nj = 0; nj < 2; ++nj) {
            const s16x8 bfr = *(const s16x8*)(smem + EXLo + (nj * 16 + r) * 256 +
                                              (((kb & 24) | ((kb ^ rx) & 7)) << 3));
            eacc[h][nj] = MFMA16(af, bfr, eacc[h][nj]);
          }
        }
      }
      SCHED_FENCE(); WAIT_LGKM(); BAR(); SCHED_FENCE();
    }
  }

  // write partial [nchunk][8192][32]
  #pragma unroll
  for (int h = 0; h < 2; ++h)
    #pragma unroll
    for (int nj = 0; nj < 2; ++nj) {
      const int rb = r0 + h * 128 + w * 16 + q * 4;
      const int cls = nj * 16 + r;
      #pragma unroll
      for (int t = 0; t < 4; ++t)
        partial[((size_t)nchunk * 8192 + rb + t) * 32 + cls] = eacc[h][nj][t];
    }
}

// ---------------- reduce 16 partials, /b, clip ----------------
__global__ void k_reduce(const float* __restrict__ partial, const float* __restrict__ bvec,
                         float* __restrict__ out) {
  const int idx = blockIdx.x * 256 + threadIdx.x;  // 229376 total
  const int row = idx / 28, c = idx - row * 28;
  float s = 0.f;
  #pragma unroll
  for (int nc = 0; nc < 16; ++nc) s += partial[((size_t)nc * 8192 + row) * 32 + c];
  out[idx] = fminf(fmaxf(s / bvec[c], 0.f), 1.f);
}

extern "C" void kernel_launch(void* const* d_in, const int* in_sizes, int n_in,
                              void* d_out, int out_size, void* d_ws, size_t ws_size,
                              hipStream_t stream) {
  const float* features    = (const float*)d_in[0];  // [8192,1024]
  const float* ex_features = (const float*)d_in[1];  // [16384,1024]
  const float* g_w         = (const float*)d_in[2];  // [512,1024]
  const float* g_b         = (const float*)d_in[3];  // [512]
  const float* ex_classes  = (const float*)d_in[4];  // [16384,28]
  float* out = (float*)d_out;
  char* ws = (char*)d_ws;

  unsigned short* featbf = (unsigned short*)(ws + 0);
  unsigned short* exbf   = (unsigned short*)(ws + 16777216);
  unsigned short* fnall  = (unsigned short*)(ws + 0);
  float* fall            = (float*)(ws + 50331648);
  float* partial         = (float*)(ws + 50331648);
  unsigned short* gwbf   = (unsigned short*)(ws + 100663296);
  unsigned short* excT   = (unsigned short*)(ws + 101711872);
  float* bvec            = (float*)(ws + 102760448);

  k_cast_bf16<<<2048, 256, 0, stream>>>(features, featbf, 8192 * 1024 / 4);
  k_cast_bf16<<<2048, 256, 0, stream>>>(ex_features, exbf, 16384 * 1024 / 4);
  k_cast_bf16<<<512, 256, 0, stream>>>(g_w, gwbf, 512 * 1024 / 4);
  k_excT<<<32, 256, 0, stream>>>(ex_classes, excT, bvec);
  k_proj<<<dim3(96, 4), 512, 0, stream>>>(featbf, exbf, gwbf, g_b, fall);
  k_norm<<<6144, 256, 0, stream>>>(fall, fnall);
  k_fused<<<dim3(32, 16), 512, 0, stream>>>(fnall, excT, partial);
  k_reduce<<<896, 256, 0, stream>>>(partial, bvec, out);
}